// Round 7
// baseline (4896.569 us; speedup 1.0000x reference)
//
#include <hip/hip_runtime.h>
#include <hip/hip_fp16.h>

typedef unsigned int u32;
typedef _Float16 h2v __attribute__((ext_vector_type(2)));

#define B_ 64
#define T_ 1024
#define H_ 512
#define I_ 512

// ---------------- fp16 dot2 helper (v_dot2_f32_f16) ----------------
__device__ __forceinline__ float dot2f(u32 w, u32 h, float acc) {
#if __has_builtin(__builtin_amdgcn_fdot2)
    return __builtin_amdgcn_fdot2(__builtin_bit_cast(h2v, w),
                                  __builtin_bit_cast(h2v, h), acc, false);
#else
    __half2 a = __builtin_bit_cast(__half2, w);
    __half2 b = __builtin_bit_cast(__half2, h);
    return acc + __low2float(a) * __low2float(b) + __high2float(a) * __high2float(b);
#endif
}

__device__ __forceinline__ u32 pkf16(float a, float b) {
    __half2 h = __floats2half2_rn(a, b);
    return __builtin_bit_cast(u32, h);
}

// ---------------- W_hh repack: wT[k2][o] = pk(W[o][2k2], W[o][2k2+1]) ----------
// k2-major so the scan's per-thread (o = tid) register preload is coalesced.
__global__ void prep_wT(const float* __restrict__ Whh, u32* __restrict__ wT) {
    const int k2 = blockIdx.x;          // 0..255
    const int o = threadIdx.x;          // 0..511
    wT[k2 * 512 + o] = pkf16(Whh[o * 512 + 2 * k2], Whh[o * 512 + 2 * k2 + 1]);
}

// ---------------- Phase 1: Xp = X @ W_ih^T + (b_ih + b_hh), into d_out -------
#define BM 128
#define BN 64

__launch_bounds__(256, 3)
__global__ void gemm_xp(const float* __restrict__ X, const float* __restrict__ Wih,
                        const float* __restrict__ bih, const float* __restrict__ bhh,
                        float* __restrict__ out) {
    __shared__ u32 Xs[16][BM + 4];   // half2 entries, k2-major
    __shared__ u32 Ws[16][BN + 4];
    const int t = threadIdx.x;
    const int bn = blockIdx.x & 7;
    const int bm = blockIdx.x >> 3;
    const int m0 = bm * BM, n0 = bn * BN;
    const int tm = t & 15, tn = t >> 4;
    float acc[8][4];
#pragma unroll
    for (int i = 0; i < 8; i++)
#pragma unroll
        for (int j = 0; j < 4; j++) acc[i][j] = 0.f;
    const int kc = t & 7, rr = t >> 3;
    const int key = ((tm >> 2) & 1) << 2;     // XOR spread (bijective)
    for (int kt = 0; kt < 16; kt++) {
        const int k0 = kt * 32;
#pragma unroll
        for (int it = 0; it < 4; it++) {
            const int m = it * 32 + rr;
            float4 v = *(const float4*)&X[(size_t)(m0 + m) * I_ + k0 + kc * 4];
            const int mp = m ^ (((m >> 5) & 1) << 2);
            Xs[kc * 2 + 0][mp] = pkf16(v.x, v.y);
            Xs[kc * 2 + 1][mp] = pkf16(v.z, v.w);
        }
#pragma unroll
        for (int it = 0; it < 2; it++) {
            const int n = it * 32 + rr;
            float4 v = *(const float4*)&Wih[(size_t)(n0 + n) * I_ + k0 + kc * 4];
            Ws[kc * 2 + 0][n] = pkf16(v.x, v.y);
            Ws[kc * 2 + 1][n] = pkf16(v.z, v.w);
        }
        __syncthreads();
#pragma unroll
        for (int k2 = 0; k2 < 16; k2++) {
            uint4 a0 = *(const uint4*)&Xs[k2][(tm * 8) ^ key];
            uint4 a1 = *(const uint4*)&Xs[k2][(tm * 8 + 4) ^ key];
            uint4 bv = *(const uint4*)&Ws[k2][tn * 4];
            u32 aa[8] = {a0.x, a0.y, a0.z, a0.w, a1.x, a1.y, a1.z, a1.w};
            u32 bb[4] = {bv.x, bv.y, bv.z, bv.w};
#pragma unroll
            for (int mi = 0; mi < 8; mi++)
#pragma unroll
                for (int ni = 0; ni < 4; ni++)
                    acc[mi][ni] = dot2f(aa[mi], bb[ni], acc[mi][ni]);
        }
        __syncthreads();
    }
    float4 b1 = *(const float4*)&bih[n0 + tn * 4];
    float4 b2 = *(const float4*)&bhh[n0 + tn * 4];
    float4 bs = {b1.x + b2.x, b1.y + b2.y, b1.z + b2.z, b1.w + b2.w};
#pragma unroll
    for (int mi = 0; mi < 8; mi++) {
        const int row = m0 + tm * 8 + mi;
        float4 st = {acc[mi][0] + bs.x, acc[mi][1] + bs.y,
                     acc[mi][2] + bs.z, acc[mi][3] + bs.w};
        *(float4*)&out[(size_t)row * H_ + n0 + tn * 4] = st;
    }
}

// ---------------- Phase 2: K-split scan, 128 blocks (2 per batch element) ----
// Block pair (2b, 2b+1): kh = blk&1 owns K-half [kh*256, kh*256+256).
// Thread o (=tid) holds W[o][k-half] as 128 fp16-pairs in REGISTERS (no LDS W,
// no spill) and computes partial[o] = sum over its half. Halves exchange 2KB
// fp32 partials per step via agent-scope atomics + flag handshake (G16), then
// both redundantly compute h = tanh(xp + p0 + p1); full h kept in 2KB LDS.
// Flags memset to 0 per launch; pbuf double-buffered by t&1 (mutual poll makes
// overwrite-before-read impossible). 8 waves @ ~165 VGPR -> 1 block/CU, 128
// blocks co-resident on 256 CUs.
__launch_bounds__(512)
__global__ void rnn_scan(const u32* __restrict__ wT, float* __restrict__ out,
                         float* __restrict__ pbuf, u32* __restrict__ flags) {
    __shared__ __align__(16) u32 hh[2][256];   // 2 x 512 fp16 (ping-pong)
    const int tid = threadIdx.x;
    const int blk = blockIdx.x;
    const int b = blk >> 1, kh = blk & 1;
    const int o = tid;

    u32 wr[128];
#pragma unroll
    for (int r = 0; r < 128; r++) wr[r] = wT[(kh * 128 + r) * 512 + o];

    ((u32*)hh)[tid] = 0u;                      // h0 = 0 (both buffers)
    __syncthreads();

    float* outb = out + (size_t)b * (T_ * H_);
    float xp = outb[o];                        // Xp[b,0,o]

    for (int t = 0; t < T_; t++) {
        const int buf = t & 1;
        float acc = 0.f;
#pragma unroll
        for (int i = 0; i < 32; i++) {
            uint4 hq = *(const uint4*)&hh[buf][kh * 128 + i * 4];  // broadcast
            acc = dot2f(wr[i * 4 + 0], hq.x, acc);
            acc = dot2f(wr[i * 4 + 1], hq.y, acc);
            acc = dot2f(wr[i * 4 + 2], hq.z, acc);
            acc = dot2f(wr[i * 4 + 3], hq.w, acc);
        }
        // ---- publish my partial (device-coherent point), handshake, read theirs
        float* pb_w = pbuf + ((size_t)buf * 128 + blk) * 512;
        float* pb_p = pbuf + ((size_t)buf * 128 + (blk ^ 1)) * 512;
        __hip_atomic_store(pb_w + o, acc, __ATOMIC_RELAXED, __HIP_MEMORY_SCOPE_AGENT);
        asm volatile("s_waitcnt vmcnt(0)" ::: "memory");   // my store acked at L2-coherent point
        __syncthreads();                                   // all 512 stores acked
        if (tid == 0) {
            __hip_atomic_store(&flags[blk], (u32)(t + 1), __ATOMIC_RELEASE,
                               __HIP_MEMORY_SCOPE_AGENT);
            while (__hip_atomic_load(&flags[blk ^ 1], __ATOMIC_ACQUIRE,
                                     __HIP_MEMORY_SCOPE_AGENT) < (u32)(t + 1)) {
                __builtin_amdgcn_s_sleep(1);
            }
        }
        __syncthreads();
        const float theirs = __hip_atomic_load(pb_p + o, __ATOMIC_RELAXED,
                                               __HIP_MEMORY_SCOPE_AGENT);
        // canonical add order (p0 first) so both halves round identically
        const float s = kh ? (theirs + acc) : (acc + theirs);
        const float pre = xp + s;
        const float e = __expf(-2.f * fabsf(pre));
        const float th = __builtin_copysignf((1.f - e) / (1.f + e), pre);
        if (!kh) outb[(size_t)t * H_ + o] = th;            // one writer per pair
        xp = (t + 1 < T_) ? outb[(size_t)(t + 1) * H_ + o] : 0.f;
        ((__half*)hh)[((buf ^ 1) << 9) + o] = __float2half(th);
        __syncthreads();                                   // h ready for next step
    }
}

extern "C" void kernel_launch(void* const* d_in, const int* in_sizes, int n_in,
                              void* d_out, int out_size, void* d_ws, size_t ws_size,
                              hipStream_t stream) {
    const float* X    = (const float*)d_in[0];
    const float* Wih  = (const float*)d_in[1];
    const float* Whh  = (const float*)d_in[2];
    const float* bih  = (const float*)d_in[3];
    const float* bhh  = (const float*)d_in[4];
    float* out = (float*)d_out;

    // d_ws layout: wT 512KB | pbuf 512KB | flags 512B  (total ~1.05MB)
    u32*   wT    = (u32*)d_ws;
    float* pbuf  = (float*)((char*)d_ws + 524288);
    u32*   flags = (u32*)((char*)d_ws + 1048576);

    hipMemsetAsync(flags, 0, 128 * sizeof(u32), stream);   // fresh handshake per launch
    prep_wT<<<dim3(256), dim3(512), 0, stream>>>(Whh, wT);
    gemm_xp<<<dim3((65536 / BM) * (H_ / BN)), dim3(256), 0, stream>>>(X, Wih, bih, bhh, out);
    rnn_scan<<<dim3(2 * B_), dim3(512), 0, stream>>>(wT, out, pbuf, flags);
}

// Round 8
// 2436.600 us; speedup vs baseline: 2.0096x; 2.0096x over previous
//
#include <hip/hip_runtime.h>
#include <hip/hip_fp16.h>

typedef unsigned int u32;
typedef unsigned long long u64;
typedef _Float16 h2v __attribute__((ext_vector_type(2)));

#define B_ 64
#define T_ 1024
#define H_ 512
#define I_ 512

// ---------------- fp16 dot2 helper (v_dot2_f32_f16) ----------------
__device__ __forceinline__ float dot2f(u32 w, u32 h, float acc) {
#if __has_builtin(__builtin_amdgcn_fdot2)
    return __builtin_amdgcn_fdot2(__builtin_bit_cast(h2v, w),
                                  __builtin_bit_cast(h2v, h), acc, false);
#else
    __half2 a = __builtin_bit_cast(__half2, w);
    __half2 b = __builtin_bit_cast(__half2, h);
    return acc + __low2float(a) * __low2float(b) + __high2float(a) * __high2float(b);
#endif
}

__device__ __forceinline__ u32 pkf16(float a, float b) {
    __half2 h = __floats2half2_rn(a, b);
    return __builtin_bit_cast(u32, h);
}

// Pair-reduce stage via DPP (verified R5): keep = bit? b : a; give = bit? a : b;
// partner (lane^d) donates exactly the acc this lane keeps.
template <int CTRL>
__device__ __forceinline__ float prs_dpp(float a, float b, bool bit) {
    float keep = bit ? b : a;
    float give = bit ? a : b;
    int gv = __builtin_bit_cast(int, give);
    float got = __builtin_bit_cast(float,
        __builtin_amdgcn_update_dpp(0, gv, CTRL, 0xF, 0xF, true));
    return keep + got;
}
__device__ __forceinline__ float prs_shfl4(float a, float b, bool bit) {
    float keep = bit ? b : a;
    float give = bit ? a : b;
    return keep + __shfl_xor(give, 4);
}

// ---------------- W_hh repack (192 reg / 64 global-L2) ----------------
// Scan thread tid: g = tid>>3 owns outputs j = g*8+o (o=0..7), sub = tid&7 owns
// K-slice [sub*64, sub*64+64) (32 half2, k5 = cc*8+k, cc=0..3, k=0..7).
// Registers (192 u32/thread): r = o*32+k5, o=0..5.
// Global (64 u32/thread, 128KB total, stays L2-hot): chunks c=0..15 of [512][4]:
//   c<8 : o=6, cc = c>>1, half = c&1   (k5 = cc*8 + half*4 + q)
//   c>=8: o=7, c8 = c-8, cc = c8>>1, half = c8&1
__global__ void prep_w(const float* __restrict__ Whh, u32* __restrict__ wreg,
                       u32* __restrict__ wglob) {
    const int tid = threadIdx.x;
    const int g = tid >> 3, sub = tid & 7;
    const int bid = blockIdx.x;
    if (bid < 192) {
        const int r = bid, o = r >> 5, k5 = r & 31;
        const int j = g * 8 + o, i = sub * 64 + 2 * k5;
        wreg[r * 512 + tid] = pkf16(Whh[j * H_ + i], Whh[j * H_ + i + 1]);
    } else {
        const int c = bid - 192;            // 0..15
        const int o = 6 + (c >> 3);
        const int c8 = c & 7, cc = c8 >> 1, half = c8 & 1;
        const int j = g * 8 + o;
        for (int q = 0; q < 4; q++) {
            const int k5 = cc * 8 + half * 4 + q;
            const int i = sub * 64 + 2 * k5;
            wglob[c * 2048 + tid * 4 + q] = pkf16(Whh[j * H_ + i], Whh[j * H_ + i + 1]);
        }
    }
}

// ---------------- Phase 1: Xp = X @ W_ih^T + (b_ih + b_hh), into d_out -------
#define BM 128
#define BN 64

__launch_bounds__(256, 3)
__global__ void gemm_xp(const float* __restrict__ X, const float* __restrict__ Wih,
                        const float* __restrict__ bih, const float* __restrict__ bhh,
                        float* __restrict__ out) {
    __shared__ u32 Xs[16][BM + 4];   // half2 entries, k2-major
    __shared__ u32 Ws[16][BN + 4];
    const int t = threadIdx.x;
    const int bn = blockIdx.x & 7;
    const int bm = blockIdx.x >> 3;
    const int m0 = bm * BM, n0 = bn * BN;
    const int tm = t & 15, tn = t >> 4;
    float acc[8][4];
#pragma unroll
    for (int i = 0; i < 8; i++)
#pragma unroll
        for (int j = 0; j < 4; j++) acc[i][j] = 0.f;
    const int kc = t & 7, rr = t >> 3;
    const int key = ((tm >> 2) & 1) << 2;     // XOR spread (bijective)
    for (int kt = 0; kt < 16; kt++) {
        const int k0 = kt * 32;
#pragma unroll
        for (int it = 0; it < 4; it++) {
            const int m = it * 32 + rr;
            float4 v = *(const float4*)&X[(size_t)(m0 + m) * I_ + k0 + kc * 4];
            const int mp = m ^ (((m >> 5) & 1) << 2);
            Xs[kc * 2 + 0][mp] = pkf16(v.x, v.y);
            Xs[kc * 2 + 1][mp] = pkf16(v.z, v.w);
        }
#pragma unroll
        for (int it = 0; it < 2; it++) {
            const int n = it * 32 + rr;
            float4 v = *(const float4*)&Wih[(size_t)(n0 + n) * I_ + k0 + kc * 4];
            Ws[kc * 2 + 0][n] = pkf16(v.x, v.y);
            Ws[kc * 2 + 1][n] = pkf16(v.z, v.w);
        }
        __syncthreads();
#pragma unroll
        for (int k2 = 0; k2 < 16; k2++) {
            uint4 a0 = *(const uint4*)&Xs[k2][(tm * 8) ^ key];
            uint4 a1 = *(const uint4*)&Xs[k2][(tm * 8 + 4) ^ key];
            uint4 bv = *(const uint4*)&Ws[k2][tn * 4];
            u32 aa[8] = {a0.x, a0.y, a0.z, a0.w, a1.x, a1.y, a1.z, a1.w};
            u32 bb[4] = {bv.x, bv.y, bv.z, bv.w};
#pragma unroll
            for (int mi = 0; mi < 8; mi++)
#pragma unroll
                for (int ni = 0; ni < 4; ni++)
                    acc[mi][ni] = dot2f(aa[mi], bb[ni], acc[mi][ni]);
        }
        __syncthreads();
    }
    float4 b1 = *(const float4*)&bih[n0 + tn * 4];
    float4 b2 = *(const float4*)&bhh[n0 + tn * 4];
    float4 bs = {b1.x + b2.x, b1.y + b2.y, b1.z + b2.z, b1.w + b2.w};
#pragma unroll
    for (int mi = 0; mi < 8; mi++) {
        const int row = m0 + tm * 8 + mi;
        float4 st = {acc[mi][0] + bs.x, acc[mi][1] + bs.y,
                     acc[mi][2] + bs.z, acc[mi][3] + bs.w};
        *(float4*)&out[(size_t)row * H_ + n0 + tn * 4] = st;
    }
}

// ---------------- Phase 2: sequential scan ----------------
// W: 192 u32/thread in regs + 64 u32/thread streamed from GLOBAL (L2-hot) with
// depth-1 JIT prefetch (one cc-block ahead, rotating across the step boundary).
// LDS carries ONLY the h ping-pong broadcast (2KB). Opaque-ptr asm per step
// defeats LICM/CSE of the loop-invariant W loads (would spill ~64 regs).

#define LDG4(c) (*(const uint4*)&wg[(c) * 2048 + (tid << 2)])

#define CCBLOCK(CO, PF0, PF1, PF2, PF3)                                         \
    {                                                                           \
        uint4 c6a = n6a, c6b = n6b, c7a = n7a, c7b = n7b;                       \
        uint4 hA = *(const uint4*)&hh[rb + ((sub * 32 + (CO)*8) ^ xorkey)];     \
        uint4 hB = *(const uint4*)&hh[rb + ((sub * 32 + (CO)*8 + 4) ^ xorkey)]; \
        n6a = LDG4(PF0); n6b = LDG4(PF1); n7a = LDG4(PF2); n7b = LDG4(PF3);     \
        u32 h8[8]  = {hA.x, hA.y, hA.z, hA.w, hB.x, hB.y, hB.z, hB.w};          \
        u32 w6c[8] = {c6a.x, c6a.y, c6a.z, c6a.w, c6b.x, c6b.y, c6b.z, c6b.w};  \
        u32 w7c[8] = {c7a.x, c7a.y, c7a.z, c7a.w, c7b.x, c7b.y, c7b.z, c7b.w};  \
        _Pragma("unroll")                                                       \
        for (int k = 0; k < 8; k++) {                                           \
            acc0 = dot2f(w2[  0 + (CO)*8 + k], h8[k], acc0);                    \
            acc1 = dot2f(w2[ 32 + (CO)*8 + k], h8[k], acc1);                    \
            acc2 = dot2f(w2[ 64 + (CO)*8 + k], h8[k], acc2);                    \
            acc3 = dot2f(w2[ 96 + (CO)*8 + k], h8[k], acc3);                    \
            acc4 = dot2f(w2[128 + (CO)*8 + k], h8[k], acc4);                    \
            acc5 = dot2f(w2[160 + (CO)*8 + k], h8[k], acc5);                    \
            acc6 = dot2f(w6c[k], h8[k], acc6);                                  \
            acc7 = dot2f(w7c[k], h8[k], acc7);                                  \
        }                                                                       \
    }

__launch_bounds__(512)
__attribute__((amdgpu_waves_per_eu(2, 2)))
__global__ void rnn_scan(const u32* __restrict__ wreg, const u32* __restrict__ wglob,
                         float* __restrict__ out) {
    __shared__ __align__(16) u32 hh[512];   // 2 x 256 half2 (ping-pong)
    const int tid = threadIdx.x;
    const int sub = tid & 7;
    u32 w2[192];
#pragma unroll
    for (int r = 0; r < 192; r++) w2[r] = wreg[r * 512 + tid];
    hh[tid] = 0u;               // h0 = 0 (both buffers zeroed)
    __syncthreads();
    float* p = out + (size_t)blockIdx.x * (T_ * H_) + tid;
    const int xorkey = sub << 2;
    __half* hhh = reinterpret_cast<__half*>(hh);
    const int wv = tid >> 1;
    const int wslot = (wv ^ (((wv >> 5) & 7) << 2)) * 2 + (tid & 1);
    const bool bb0 = (sub & 1) != 0, bb1 = (sub & 2) != 0, bb2 = (sub & 4) != 0;

    u64 wga = (u64)wglob;
    {   // prologue: prime cc=0 quads (chunks 0,1,8,9)
        const u32* wg = (const u32*)wga;
        (void)wg;
    }
    const u32* wgp = (const u32*)wga;
    uint4 n6a = (*(const uint4*)&wgp[0 * 2048 + (tid << 2)]);
    uint4 n6b = (*(const uint4*)&wgp[1 * 2048 + (tid << 2)]);
    uint4 n7a = (*(const uint4*)&wgp[8 * 2048 + (tid << 2)]);
    uint4 n7b = (*(const uint4*)&wgp[9 * 2048 + (tid << 2)]);

    for (int t = 0; t < T_; t++) {
        asm volatile("" : "+s"(wga));        // opaque base: no LICM/CSE of W loads
        const u32* wg = (const u32*)wga;
        const float xp = *p;                 // consumed at tail
        const int rb = (t & 1) << 8;
        float acc0 = 0.f, acc1 = 0.f, acc2 = 0.f, acc3 = 0.f;
        float acc4 = 0.f, acc5 = 0.f, acc6 = 0.f, acc7 = 0.f;
        CCBLOCK(0, 2, 3, 10, 11)             // consume cc0, prefetch cc1
        CCBLOCK(1, 4, 5, 12, 13)             // consume cc1, prefetch cc2
        CCBLOCK(2, 6, 7, 14, 15)             // consume cc2, prefetch cc3
        CCBLOCK(3, 0, 1, 8, 9)               // consume cc3, prefetch next-t cc0
        // butterfly pair-reduce (R5-verified); lane ends holding its own acc[sub]
        float s0 = prs_dpp<0xB1>(acc0, acc1, bb0);
        float s2 = prs_dpp<0xB1>(acc2, acc3, bb0);
        float s4 = prs_dpp<0xB1>(acc4, acc5, bb0);
        float s6 = prs_dpp<0xB1>(acc6, acc7, bb0);
        float u0 = prs_dpp<0x4E>(s0, s2, bb1);
        float u4 = prs_dpp<0x4E>(s4, s6, bb1);
        float r  = prs_shfl4(u0, u4, bb2);
        const float pre = xp + r;
        const float e = __expf(-2.f * fabsf(pre));
        const float th = __builtin_copysignf((1.f - e) / (1.f + e), pre);
        *p = th;                             // overwrite Xp[b,t,tid] with h_t
        p += H_;
        hhh[(((t & 1) ^ 1) << 9) + wslot] = __float2half(th);
        asm volatile("s_waitcnt lgkmcnt(0)" ::: "memory");
        __builtin_amdgcn_sched_barrier(0);
        __builtin_amdgcn_s_barrier();        // does NOT drain vmcnt: W prefetch flies on
        __builtin_amdgcn_sched_barrier(0);
    }
}

extern "C" void kernel_launch(void* const* d_in, const int* in_sizes, int n_in,
                              void* d_out, int out_size, void* d_ws, size_t ws_size,
                              hipStream_t stream) {
    const float* X    = (const float*)d_in[0];
    const float* Wih  = (const float*)d_in[1];
    const float* Whh  = (const float*)d_in[2];
    const float* bih  = (const float*)d_in[3];
    const float* bhh  = (const float*)d_in[4];
    float* out = (float*)d_out;
    // workspace: 98304 dwords wreg (384KB) + 32768 dwords wglob (128KB) = 512KB
    u32* wreg  = (u32*)d_ws;
    u32* wglob = wreg + 98304;

    prep_w<<<dim3(208), dim3(512), 0, stream>>>(Whh, wreg, wglob);
    gemm_xp<<<dim3((65536 / BM) * (H_ / BN)), dim3(256), 0, stream>>>(X, Wih, bih, bhh, out);
    rnn_scan<<<dim3(B_), dim3(512), 0, stream>>>(wreg, wglob, out);
}